// Round 1
// baseline (151.781 us; speedup 1.0000x reference)
//
#include <hip/hip_runtime.h>

#define TAU_F    0.1f
#define N_ITERS  1000
#define EPS_F    1e-8f
#define LOG2E_F  1.44269504088896340736f
#define LN2_F    0.69314718055994530942f

// Raw transcendental units (pure, CSE-able: no volatile).
__device__ __forceinline__ float fexp2(float x){ float r; asm("v_exp_f32 %0, %1" : "=v"(r) : "v"(x)); return r; }
__device__ __forceinline__ float flog2(float x){ float r; asm("v_log_f32 %0, %1" : "=v"(r) : "v"(x)); return r; }
__device__ __forceinline__ float frcp (float x){ float r; asm("v_rcp_f32 %0, %1" : "=v"(r) : "v"(x)); return r; }

// Swap value with adjacent lane (xor 1) via DPP quad_perm [1,0,3,2] — VALU, no LDS.
__device__ __forceinline__ float swap_adj(float x){
  int xi = __builtin_bit_cast(int, x);
  int rr = __builtin_amdgcn_update_dpp(xi, xi, 0xB1, 0xF, 0xF, false);
  return __builtin_bit_cast(float, rr);
}

// Thread t: row r = t>>1, player p = t&1 (0 = u/maximizer, 1 = v/minimizer).
// Each lane keeps its own strategy y[4]; the opponent's strategy arrives by DPP swap.
__global__ __launch_bounds__(64, 1) void soccer_kernel(
    const float* __restrict__ x, const float* __restrict__ W,
    const float* __restrict__ P, float* __restrict__ out, int N)
{
  const int t = blockIdx.x * 64 + threadIdx.x;
  const int r = t >> 1;
  const int p = t & 1;
  if (r >= N) return;

  const float xv = x[r];
  // lam for this lane: columns (2p, 2p+1) of j = exp(x*W^T) + EPS
  const float w0 = W[2 * p + 0], w1 = W[2 * p + 1];
  const float l0 = fexp2(xv * (w0 * LOG2E_F)) + EPS_F;
  const float l1 = fexp2(xv * (w1 * LOG2E_F)) + EPS_F;

  // Per-lane payoff matrix, sign folded in:  z_c = sum_k M[c][k] * other_k
  //   u-lane: z = gu = v @ P^T          -> M[c][k] = +P[c][k]
  //   v-lane: z = -gv, gv = u @ P       -> M[c][k] = -P[k][c]
  float M[4][4];
#pragma unroll
  for (int c = 0; c < 4; ++c) {
#pragma unroll
    for (int k = 0; k < 4; ++k) {
      const float pu = P[c * 4 + k];
      const float pv = -P[k * 4 + c];
      M[c][k] = (p == 0) ? pu : pv;
    }
  }

  // Precomputed per-lane scales (hoist all divisions/log2e folds out of the loop).
  const float c_in   = l1 * LOG2E_F;     // inner exp2 scale
  const float c_lse  = LN2_F / l1;       // J1 = mx + log2(s)*c_lse
  const float c_outn = -(l0 * LOG2E_F);  // outer sigmoid exponent scale

  float y0 = 0.5f, y1 = 0.5f, y2 = 0.25f, y3 = 0.25f;

  for (int it = 0; it < N_ITERS; ++it) {
    const float o0 = swap_adj(y0);
    const float o1 = swap_adj(y1);
    const float o2 = swap_adj(y2);
    const float o3 = swap_adj(y3);

    const float z0 = fmaf(M[0][0], o0, fmaf(M[0][1], o1, fmaf(M[0][2], o2, M[0][3] * o3)));
    const float z1 = fmaf(M[1][0], o0, fmaf(M[1][1], o1, fmaf(M[1][2], o2, M[1][3] * o3)));
    const float z2 = fmaf(M[2][0], o0, fmaf(M[2][1], o1, fmaf(M[2][2], o2, M[2][3] * o3)));
    const float z3 = fmaf(M[3][0], o0, fmaf(M[3][1], o1, fmaf(M[3][2], o2, M[3][3] * o3)));

    // Inner infoset {2,3}: softmax + logsumexp/l1 in one exp + one log + one rcp.
    const float mx  = fmaxf(z2, z3);
    const float mn  = fminf(z2, z3);
    const float e   = fexp2(c_in * (mn - mx));   // in (0,1]; underflow->0 is exact
    const float s   = 1.0f + e;
    const float rs  = frcp(s);
    const float J1  = fmaf(flog2(s), c_lse, mx); // = max(z2,z3) + log(1+e)/l1
    const float plo = e * rs;
    const bool  c23 = (z2 >= z3);
    const float p2  = c23 ? rs  : plo;
    const float p3  = c23 ? plo : rs;

    // Root infoset {0,1}: p01[1] = sigmoid(l0*((z1+J1) - z0)); inf-safe.
    const float dd = (z1 + J1) - z0;
    const float e2 = fexp2(c_outn * dd);
    const float b1 = frcp(1.0f + e2);
    const float b0 = 1.0f - b1;

    // y += TAU * (b - y)
    y0 = fmaf(TAU_F, b0 - y0, y0);
    y1 = fmaf(TAU_F, b1 - y1, y1);
    y2 = fmaf(TAU_F, fmaf(b1, p2, -y2), y2);
    y3 = fmaf(TAU_F, fmaf(b1, p3, -y3), y3);
  }

  // Output layout: [ u : N*4 | v : N*4 | j : N*4 ], all fp32.
  float4* uv = (float4*)out;
  uv[(size_t)p * N + r] = make_float4(y0, y1, y2, y3);
  // This lane owns j columns (2p, 2p+1) of its row -> contiguous float2 at index t.
  float2* jj = (float2*)(out + (size_t)8 * N);
  jj[t] = make_float2(l0, l1);
}

extern "C" void kernel_launch(void* const* d_in, const int* in_sizes, int n_in,
                              void* d_out, int out_size, void* d_ws, size_t ws_size,
                              hipStream_t stream) {
  const float* x = (const float*)d_in[0];
  const float* W = (const float*)d_in[1];
  const float* P = (const float*)d_in[2];
  float* out = (float*)d_out;
  const int N = in_sizes[0];          // 8192 rows
  const int threads = 2 * N;          // 2 lanes per row
  dim3 block(64);                     // 1 wave per block -> spread across all 256 CUs
  dim3 grid((threads + 63) / 64);
  hipLaunchKernelGGL(soccer_kernel, grid, block, 0, stream, x, W, P, out, N);
}

// Round 2
// 133.069 us; speedup vs baseline: 1.1406x; 1.1406x over previous
//
#include <hip/hip_runtime.h>

#define TAU_F      0.1f
#define OMT_F      0.9f           // 1 - TAU
#define N_ITERS    1000
#define EPS_F      1e-8f
#define LOG2E_F    1.44269504088896340736f

// Raw transcendental units (pure, CSE-able: no volatile).
__device__ __forceinline__ float fexp2(float x){ float r; asm("v_exp_f32 %0, %1" : "=v"(r) : "v"(x)); return r; }
__device__ __forceinline__ float flog2(float x){ float r; asm("v_log_f32 %0, %1" : "=v"(r) : "v"(x)); return r; }
__device__ __forceinline__ float frcp (float x){ float r; asm("v_rcp_f32 %0, %1" : "=v"(r) : "v"(x)); return r; }

// Swap value with adjacent lane (xor 1) via DPP quad_perm [1,0,3,2].
__device__ __forceinline__ float swap_adj(float x){
  int xi = __builtin_bit_cast(int, x);
  int rr = __builtin_amdgcn_update_dpp(xi, xi, 0xB1, 0xF, 0xF, false);
  return __builtin_bit_cast(float, rr);
}

// Thread t: row r = t>>1, player p = t&1 (0 = u/maximizer, 1 = v/minimizer).
// Pe (embedded payoff matrix) has row 1 and column 1 identically zero:
//   -> z1 == 0 always, and the opponent's y1 is never consumed (only o0,o2,o3).
// Per-lane scaled matrix A = diag(kappa, -, c_in, c_in) * M over columns {0,2,3}:
//   u-lane: M[c][k] = +P[c][k];  v-lane: M[c][k] = -P[k][c]  (sign folded).
// Inner infoset on scaled scores z~ = c_in*z; outer sigmoid exponent:
//   t2 = z~0 - rho*(max(z~2,z~3) + log2(1+e))   with rho = l0/l1.
__global__ __launch_bounds__(64, 1) void soccer_kernel(
    const float* __restrict__ x, const float* __restrict__ W,
    const float* __restrict__ P, float* __restrict__ out, int N)
{
  const int t = blockIdx.x * 64 + threadIdx.x;
  const int r = t >> 1;
  const int p = t & 1;
  if (r >= N) return;

  const float xv = x[r];
  const float w0 = W[2 * p + 0], w1 = W[2 * p + 1];
  const float l0 = fexp2(xv * (w0 * LOG2E_F)) + EPS_F;
  const float l1 = fexp2(xv * (w1 * LOG2E_F)) + EPS_F;

  const float kappa = l0 * LOG2E_F;   // bake into row 0
  const float cin   = l1 * LOG2E_F;   // bake into rows 2,3
  const float rho   = l0 / l1;        // full-precision divide, once

  // Build per-lane scaled coefficients (cols {0,2,3} only; col 1 of Pe is 0).
  float A00, A02, A03, A20, A22, A23, A30, A32, A33;
  {
    auto m = [&](int c, int k) -> float {
      const float pu = P[c * 4 + k];
      const float pv = -P[k * 4 + c];
      return (p == 0) ? pu : pv;
    };
    A00 = kappa * m(0,0); A02 = kappa * m(0,2); A03 = kappa * m(0,3);
    A20 = cin   * m(2,0); A22 = cin   * m(2,2); A23 = cin   * m(2,3);
    A30 = cin   * m(3,0); A32 = cin   * m(3,2); A33 = cin   * m(3,3);
  }

  float y0 = 0.5f, y1 = 0.5f, y2 = 0.25f, y3 = 0.25f;

  for (int it = 0; it < N_ITERS; ++it) {
    // Opponent strategy (y1 never needed).
    const float o0 = swap_adj(y0);
    const float o2 = swap_adj(y2);
    const float o3 = swap_adj(y3);

    // Pre-scaled scores (z~0 = kappa*z0; z~2/3 = cin*z2/3). Depth: mul,fma,fma.
    const float z0 = fmaf(A00, o0, fmaf(A02, o2, A03 * o3));
    const float z2 = fmaf(A20, o0, fmaf(A22, o2, A23 * o3));
    const float z3 = fmaf(A30, o0, fmaf(A32, o2, A33 * o3));

    // Inner infoset {2,3}: already in log2 domain.
    const float mx  = fmaxf(z2, z3);
    const float mn  = fminf(z2, z3);
    const float e   = fexp2(mn - mx);      // (0,1]; underflow->0 exact
    const float s   = 1.0f + e;
    const float rs  = frcp(s);             // parallel branch
    const float plo = e * rs;
    const bool  c23 = (z2 >= z3);
    const float p2  = c23 ? rs  : plo;
    const float p3  = c23 ? plo : rs;
    const float lg  = flog2(s);

    // Outer sigmoid: t2 = z~0 - rho*(mx + lg); `base` is off the exp/log path.
    const float base = fmaf(-rho, mx, z0);
    const float t2   = fmaf(-rho, lg, base);
    const float e2   = fexp2(t2);
    const float b1   = frcp(1.0f + e2);    // inf-safe: rcp(inf)=0

    // y' = (1-tau)*y + tau*b  — only ONE fma after b1 on each path.
    const float f0 = fmaf(OMT_F, y0, TAU_F);   // parallel
    const float m1 = OMT_F * y1;               // parallel
    const float q2 = TAU_F * p2;               // parallel (p2 ready early)
    const float q3 = TAU_F * p3;               // parallel
    const float m2 = OMT_F * y2;               // parallel
    const float m3 = OMT_F * y3;               // parallel
    y0 = fmaf(-TAU_F, b1, f0);
    y1 = fmaf( TAU_F, b1, m1);
    y2 = fmaf(q2, b1, m2);
    y3 = fmaf(q3, b1, m3);
  }

  // Output layout: [ u : N*4 | v : N*4 | j : N*4 ], all fp32.
  float4* uv = (float4*)out;
  uv[(size_t)p * N + r] = make_float4(y0, y1, y2, y3);
  float2* jj = (float2*)(out + (size_t)8 * N);
  jj[t] = make_float2(l0, l1);
}

extern "C" void kernel_launch(void* const* d_in, const int* in_sizes, int n_in,
                              void* d_out, int out_size, void* d_ws, size_t ws_size,
                              hipStream_t stream) {
  const float* x = (const float*)d_in[0];
  const float* W = (const float*)d_in[1];
  const float* P = (const float*)d_in[2];
  float* out = (float*)d_out;
  const int N = in_sizes[0];          // 8192 rows
  const int threads = 2 * N;          // 2 lanes per row
  dim3 block(64);                     // 1 wave per block -> spread across all 256 CUs
  dim3 grid((threads + 63) / 64);
  hipLaunchKernelGGL(soccer_kernel, grid, block, 0, stream, x, W, P, out, N);
}